// Round 6
// baseline (13179.587 us; speedup 1.0000x reference)
//
#include <hip/hip_runtime.h>
#include <hip/hip_bf16.h>

#define RNN_B 64
#define RNN_S 512
#define RNN_H 1024
#define NBLK 64
#define FLAG_STRIDE 32   // one flag per 128B line
#define OUTS_ELEMS ((size_t)RNN_B * RNN_S * RNN_H)

typedef __attribute__((ext_vector_type(4))) float f32x4;
typedef __attribute__((ext_vector_type(8))) short bf16x8;
typedef __attribute__((ext_vector_type(4))) int i32x4;

// CK-style raw buffer load intrinsic (coalesced dwordx4, cachepolicy arg).
// cachepolicy 17 = SC0|SC1 on gfx950: bypass L1+L2, read the coherence point
// (LLC) -> always-fresh cross-XCD data, burst BW, compiler-tracked vmcnt.
__device__ f32x4 __rnn_rawbufload_x4(i32x4 srsrc, int voffset, int soffset,
                                     int cachepolicy) __asm("llvm.amdgcn.raw.buffer.load.v4f32");

__device__ __forceinline__ i32x4 make_srd(const void* p, unsigned bytes) {
  i32x4 r;
  r[0] = (int)(unsigned)(unsigned long long)p;
  r[1] = (int)((unsigned long long)p >> 32);   // stride=0
  r[2] = (int)bytes;                            // num_records (bytes)
  r[3] = 0x00020000;                            // raw untyped dword
  return r;
}

__device__ __forceinline__ bf16x8 ld_h(i32x4 srd, int byteoff) {
  union { f32x4 f; bf16x8 s; } u;
  u.f = __rnn_rawbufload_x4(srd, byteoff, 0, 17 /*sc0|sc1*/);
  return u.s;
}

__device__ __forceinline__ short f2bf(float f) {
  union { float f; unsigned u; } v; v.f = f;
  return (short)((v.u + 0x7FFFu + ((v.u >> 16) & 1u)) >> 16);
}
__device__ __forceinline__ float bf2f(short h) {
  union { unsigned u; float f; } v; v.u = ((unsigned)(unsigned short)h) << 16;
  return v.f;
}

__device__ __forceinline__ f32x4 mfma16(bf16x8 a, bf16x8 b, f32x4 c) {
  return __builtin_amdgcn_mfma_f32_16x16x32_bf16(a, b, c, 0, 0, 0);
}

// 2B write-through store to the coherence point: leaves nothing dirty in L2,
// so no wbl2/inv fences are ever needed for the h hand-off.
__device__ __forceinline__ void st_sys_u16(void* p, unsigned v) {
  asm volatile("global_store_short %0, %1, off sc0 sc1" :: "v"(p), "v"(v) : "memory");
}

// split 8 fp32 -> hi bf16x8 + lo bf16x8 (two-term bf16 expansion, ~16 mantissa bits)
__device__ __forceinline__ void cvt8_hl(const float* f, bf16x8* hi, bf16x8* lo) {
  #pragma unroll
  for (int i = 0; i < 8; ++i) {
    short h = f2bf(f[i]);
    (*hi)[i] = h;
    (*lo)[i] = f2bf(f[i] - bf2f(h));
  }
}

// ---------- Kernel 1: A0 = x @ W_ih0^T + b_ih0 + b_hh0 (split-bf16 3-pass, ~fp32 accurate)
__global__ __launch_bounds__(256) void a0_gemm(
    const float* __restrict__ x, const float* __restrict__ Wih0,
    const float* __restrict__ bih0, const float* __restrict__ bhh0,
    float* __restrict__ A0, unsigned* __restrict__ flags)
{
  if (blockIdx.x == 0) {
    for (int i = threadIdx.x; i < NBLK * FLAG_STRIDE; i += 256)
      __hip_atomic_store(&flags[i], 0u, __ATOMIC_RELAXED, __HIP_MEMORY_SCOPE_SYSTEM);
  }
  const int bn = blockIdx.x & 7;     // 8 N-tiles of 128
  const int bm = blockIdx.x >> 3;    // 256 M-tiles of 128
  const int tid = threadIdx.x;
  const int lane = tid & 63;
  const int w = tid >> 6;
  const int wr = w >> 1, wc = w & 1;
  const int l15 = lane & 15, lq = lane >> 4;

  __shared__ short As[2][128][40];   // [hi/lo][row][k], +8 pad
  __shared__ short Bs[2][128][40];

  f32x4 acc[4][4] = {};

  const int sr = tid >> 1;
  const int sc = (tid & 1) << 4;
  const float* xp = x + (size_t)(bm * 128 + sr) * RNN_H + sc;
  const float* wp = Wih0 + (size_t)(bn * 128 + sr) * RNN_H + sc;

  for (int k0 = 0; k0 < RNN_H; k0 += 32) {
    float xa[16], wa[16];
    #pragma unroll
    for (int j = 0; j < 4; ++j) {
      *(float4*)&xa[j * 4] = *(const float4*)(xp + k0 + j * 4);
      *(float4*)&wa[j * 4] = *(const float4*)(wp + k0 + j * 4);
    }
    __syncthreads();   // previous iter's LDS reads done
    bf16x8 h0, l0, h1, l1;
    cvt8_hl(&xa[0], &h0, &l0); cvt8_hl(&xa[8], &h1, &l1);
    *(bf16x8*)&As[0][sr][sc] = h0; *(bf16x8*)&As[1][sr][sc] = l0;
    *(bf16x8*)&As[0][sr][sc + 8] = h1; *(bf16x8*)&As[1][sr][sc + 8] = l1;
    cvt8_hl(&wa[0], &h0, &l0); cvt8_hl(&wa[8], &h1, &l1);
    *(bf16x8*)&Bs[0][sr][sc] = h0; *(bf16x8*)&Bs[1][sr][sc] = l0;
    *(bf16x8*)&Bs[0][sr][sc + 8] = h1; *(bf16x8*)&Bs[1][sr][sc + 8] = l1;
    __syncthreads();
    bf16x8 ah[4], al[4], bh[4], bl[4];
    #pragma unroll
    for (int i = 0; i < 4; ++i) {
      ah[i] = *(const bf16x8*)&As[0][wr * 64 + i * 16 + l15][lq * 8];
      al[i] = *(const bf16x8*)&As[1][wr * 64 + i * 16 + l15][lq * 8];
    }
    #pragma unroll
    for (int j = 0; j < 4; ++j) {
      bh[j] = *(const bf16x8*)&Bs[0][wc * 64 + j * 16 + l15][lq * 8];
      bl[j] = *(const bf16x8*)&Bs[1][wc * 64 + j * 16 + l15][lq * 8];
    }
    #pragma unroll
    for (int i = 0; i < 4; ++i)
      #pragma unroll
      for (int j = 0; j < 4; ++j) {
        acc[i][j] = mfma16(ah[i], bh[j], acc[i][j]);
        acc[i][j] = mfma16(al[i], bh[j], acc[i][j]);
        acc[i][j] = mfma16(ah[i], bl[j], acc[i][j]);
      }
  }

  #pragma unroll
  for (int j = 0; j < 4; ++j) {
    const int col = bn * 128 + wc * 64 + j * 16 + l15;
    const float bias = bih0[col] + bhh0[col];
    #pragma unroll
    for (int i = 0; i < 4; ++i) {
      const int row0 = bm * 128 + wr * 64 + i * 16 + lq * 4;
      #pragma unroll
      for (int r = 0; r < 4; ++r)
        A0[(size_t)(row0 + r) * RNN_H + col] = acc[i][j][r] + bias;
    }
  }
}

// ---------- grid barrier: no cache-maintenance fences. All cross-block data moves
// via sc0/sc1 coherence-point ops; barrier = drain stores -> flag store -> poll.
__device__ __forceinline__ void gbar(unsigned* flags, unsigned target, int bid) {
  asm volatile("s_waitcnt vmcnt(0)" ::: "memory");  // drain this wave's asm h-stores
  __syncthreads();                                   // all waves arrived + drained
  if (threadIdx.x == 0)
    __hip_atomic_store(&flags[bid * FLAG_STRIDE], target,
                       __ATOMIC_RELAXED, __HIP_MEMORY_SCOPE_SYSTEM);
  if (threadIdx.x < 64) {
    const unsigned* f = &flags[threadIdx.x * FLAG_STRIDE];
    while (!__all(__hip_atomic_load(f, __ATOMIC_RELAXED,
                                    __HIP_MEMORY_SCOPE_SYSTEM) >= target))
      __builtin_amdgcn_s_sleep(1);
  }
  __syncthreads();
}

// ---------- Kernel 2: persistent pipelined recurrence (h carried as bf16 hi+lo pairs)
// launch_bounds(512, 2): 8 waves/CU = 2/EU -> VGPR cap 256, so the 2-deep
// chunked staging (X/Y register arrays, 16-32 loads in flight) fits.
__global__ __launch_bounds__(512, 2) void rnn_rec(
    const float* __restrict__ Whh0,
    const float* __restrict__ Wih1, const float* __restrict__ bih1,
    const float* __restrict__ Whh1, const float* __restrict__ bhh1,
    float* outs,             // d_out: A0 (read), layer-1 outs (write), hT tail
    short* __restrict__ h0hi, short* __restrict__ h0lo,
    short* __restrict__ h1hi, short* __restrict__ h1lo,
    unsigned* flags)
{
  const int bid = blockIdx.x;
  const int n0 = bid * 16;
  const int tid = threadIdx.x;
  const int w = tid >> 6;
  const int lane = tid & 63;
  const int l15 = lane & 15;
  const int lq = lane >> 4;
  const int mt = (w & 3) * 16;      // batch-row tile for this wave
  const bool isL1 = w >= 4;
  const int BH = RNN_B * RNN_H;
  const unsigned HBYTES = 2u * (unsigned)BH * 2u;   // bytes per ping-pong h buffer

  const i32x4 srd_h0hi = make_srd(h0hi, HBYTES);
  const i32x4 srd_h0lo = make_srd(h0lo, HBYTES);
  const i32x4 srd_h1hi = make_srd(h1hi, HBYTES);
  const i32x4 srd_h1lo = make_srd(h1lo, HBYTES);

  __shared__ short Ws[3 * 16 * 1024];   // 96 KiB: [Whh0 | Wih1 | Whh1], swizzled

  {
    const float* srcs[3] = { Whh0, Wih1, Whh1 };
    const int n = tid >> 5;             // 0..15
    const int kb = (tid & 31) * 32;     // 0..992
    #pragma unroll
    for (int mi = 0; mi < 3; ++mi) {
      const float* src = srcs[mi] + (size_t)(n0 + n) * RNN_H + kb;
      short* dst = &Ws[mi * 16 * 1024 + n * 1024];
      #pragma unroll
      for (int j = 0; j < 4; ++j) {
        float4 f0 = *(const float4*)(src + j * 8);
        float4 f1 = *(const float4*)(src + j * 8 + 4);
        float tmp[8]; *(float4*)&tmp[0] = f0; *(float4*)&tmp[4] = f1;
        bf16x8 hv, lv; cvt8_hl(tmp, &hv, &lv);
        const int c = (kb >> 3) + j;
        *(bf16x8*)&dst[((c ^ (n & 7)) << 3)] = hv;
      }
    }
  }
  const float bias1v = bih1[n0 + l15] + bhh1[n0 + l15];
  float* hT = outs + OUTS_ELEMS;
  __syncthreads();

  float a0v[4];
  if (!isL1) {
    #pragma unroll
    for (int r = 0; r < 4; ++r)
      a0v[r] = outs[((size_t)(mt + lq * 4 + r) * RNN_S + 0) * RNN_H + n0 + l15];
  }

  for (int p = 0; p <= RNN_S; ++p) {
    if (!isL1) {
      if (p < RNN_S) {
        // layer 0: h0(p) = tanh(A0[:,p,:] + h0(p-1) @ Whh0^T) for cols n0..n0+15
        f32x4 acc0 = { a0v[0], a0v[1], a0v[2], a0v[3] };
        f32x4 acc1 = {};
        if (p > 0) {
          const int hb = (((p - 1) & 1) * BH + (mt + l15) * RNN_H + lq * 8) * 2;
          const short* wrow = &Ws[l15 * 1024];
          const int swz = l15 & 7;
          // 2-deep pipelined staging: 8 K-steps/chunk, hi+lo = 16 frags/chunk
          auto stage = [&](bf16x8* bh2, bf16x8* bl2, int ks0) {
            #pragma unroll
            for (int i = 0; i < 8; ++i) {
              bh2[i] = ld_h(srd_h0hi, hb + (ks0 + i) * 64);
              bl2[i] = ld_h(srd_h0lo, hb + (ks0 + i) * 64);
            }
          };
          auto domfma = [&](const bf16x8* bh2, const bf16x8* bl2, int ks0) {
            #pragma unroll
            for (int i = 0; i < 8; ++i) {
              const int ks = ks0 + i;
              const int c = ((ks * 4 + lq) ^ swz) << 3;
              bf16x8 wv = *(const bf16x8*)(wrow + c);
              acc0 = mfma16(bh2[i], wv, acc0);
              acc1 = mfma16(bl2[i], wv, acc1);
            }
          };
          bf16x8 Xh[8], Xl[8], Yh[8], Yl[8];
          stage(Xh, Xl, 0);
          stage(Yh, Yl, 8);
          domfma(Xh, Xl, 0);
          stage(Xh, Xl, 16);
          domfma(Yh, Yl, 8);
          stage(Yh, Yl, 24);
          domfma(Xh, Xl, 16);
          domfma(Yh, Yl, 24);
        }
        acc0 += acc1;
        float vals[4];
        #pragma unroll
        for (int r = 0; r < 4; ++r) vals[r] = tanhf(acc0[r]);
        const size_t hd = (size_t)(p & 1) * BH;
        #pragma unroll
        for (int r = 0; r < 4; ++r) {
          const int idx = (mt + lq * 4 + r) * RNN_H + n0 + l15;
          short hi = f2bf(vals[r]);
          st_sys_u16(&h0hi[hd + idx], (unsigned)(unsigned short)hi);
          st_sys_u16(&h0lo[hd + idx], (unsigned)(unsigned short)f2bf(vals[r] - bf2f(hi)));
        }
        if (p == RNN_S - 1) {
          #pragma unroll
          for (int r = 0; r < 4; ++r)
            hT[(size_t)(mt + lq * 4 + r) * RNN_H + n0 + l15] = vals[r];
        }
        if (p + 1 < RNN_S) {   // prefetch next A0 (barrier-independent; drains inside gbar)
          #pragma unroll
          for (int r = 0; r < 4; ++r)
            a0v[r] = outs[((size_t)(mt + lq * 4 + r) * RNN_S + (p + 1)) * RNN_H + n0 + l15];
        }
      }
    } else {
      if (p >= 1) {
        // layer 1: t = p-1: h1(t) = tanh(b1 + h0(t) @ Wih1^T + h1(t-1) @ Whh1^T)
        const int t = p - 1;
        f32x4 acc0 = { bias1v, bias1v, bias1v, bias1v };
        f32x4 acc1 = {}, acc2 = {}, acc3 = {};
        const int h0b = ((t & 1) * BH + (mt + l15) * RNN_H + lq * 8) * 2;
        const short* wih = &Ws[16 * 1024 + l15 * 1024];
        const short* whh = &Ws[2 * 16 * 1024 + l15 * 1024];
        const int swz = l15 & 7;
        if (t > 0) {
          const int h1b = (((t - 1) & 1) * BH + (mt + l15) * RNN_H + lq * 8) * 2;
          // 2-deep pipelined staging: 4 K-steps/chunk x 4 srcs = 16 frags/chunk
          auto stage = [&](bf16x8* b, int ks0) {
            #pragma unroll
            for (int i = 0; i < 4; ++i) {
              b[i * 4 + 0] = ld_h(srd_h0hi, h0b + (ks0 + i) * 64);
              b[i * 4 + 1] = ld_h(srd_h0lo, h0b + (ks0 + i) * 64);
              b[i * 4 + 2] = ld_h(srd_h1hi, h1b + (ks0 + i) * 64);
              b[i * 4 + 3] = ld_h(srd_h1lo, h1b + (ks0 + i) * 64);
            }
          };
          auto domfma = [&](const bf16x8* b, int ks0) {
            #pragma unroll
            for (int i = 0; i < 4; ++i) {
              const int ks = ks0 + i;
              const int c = ((ks * 4 + lq) ^ swz) << 3;
              bf16x8 wi = *(const bf16x8*)(wih + c);
              bf16x8 wh = *(const bf16x8*)(whh + c);
              acc0 = mfma16(b[i * 4 + 0], wi, acc0);
              acc1 = mfma16(b[i * 4 + 1], wi, acc1);
              acc2 = mfma16(b[i * 4 + 2], wh, acc2);
              acc3 = mfma16(b[i * 4 + 3], wh, acc3);
            }
          };
          bf16x8 X[16], Y[16];
          stage(X, 0);
          stage(Y, 4);  domfma(X, 0);
          stage(X, 8);  domfma(Y, 4);
          stage(Y, 12); domfma(X, 8);
          stage(X, 16); domfma(Y, 12);
          stage(Y, 20); domfma(X, 16);
          stage(X, 24); domfma(Y, 20);
          stage(Y, 28); domfma(X, 24);
          domfma(Y, 28);
        } else {
          #pragma unroll
          for (int ks = 0; ks < 32; ++ks) {
            const int c = ((ks * 4 + lq) ^ swz) << 3;
            acc0 = mfma16(ld_h(srd_h0hi, h0b + ks * 64), *(const bf16x8*)(wih + c), acc0);
            acc1 = mfma16(ld_h(srd_h0lo, h0b + ks * 64), *(const bf16x8*)(wih + c), acc1);
          }
        }
        acc0 += acc1; acc2 += acc3; acc0 += acc2;
        float vals[4];
        #pragma unroll
        for (int r = 0; r < 4; ++r) vals[r] = tanhf(acc0[r]);
        const size_t hd = (size_t)(t & 1) * BH;
        #pragma unroll
        for (int r = 0; r < 4; ++r) {
          const int b = mt + lq * 4 + r;
          const int idx = b * RNN_H + n0 + l15;
          short hi = f2bf(vals[r]);
          st_sys_u16(&h1hi[hd + idx], (unsigned)(unsigned short)hi);
          st_sys_u16(&h1lo[hd + idx], (unsigned)(unsigned short)f2bf(vals[r] - bf2f(hi)));
          outs[((size_t)b * RNN_S + t) * RNN_H + n0 + l15] = vals[r];
        }
        if (t == RNN_S - 1) {
          #pragma unroll
          for (int r = 0; r < 4; ++r)
            hT[(size_t)RNN_B * RNN_H + (mt + lq * 4 + r) * RNN_H + n0 + l15] = vals[r];
        }
      }
    }
    if (p < RNN_S) gbar(flags, (unsigned)(p + 1), bid);
  }
}

extern "C" void kernel_launch(void* const* d_in, const int* in_sizes, int n_in,
                              void* d_out, int out_size, void* d_ws, size_t ws_size,
                              hipStream_t stream) {
  const float* x    = (const float*)d_in[0];
  const float* Wih0 = (const float*)d_in[1];
  const float* bih0 = (const float*)d_in[2];
  const float* Whh0 = (const float*)d_in[3];
  const float* bhh0 = (const float*)d_in[4];
  const float* Wih1 = (const float*)d_in[5];
  const float* bih1 = (const float*)d_in[6];
  const float* Whh1 = (const float*)d_in[7];
  const float* bhh1 = (const float*)d_in[8];
  float* outs = (float*)d_out;

  const int BH2 = 2 * RNN_B * RNN_H;               // elems per ping-pong buffer
  short* h0hi = (short*)d_ws;
  short* h0lo = h0hi + BH2;
  short* h1hi = h0lo + BH2;
  short* h1lo = h1hi + BH2;
  unsigned* flags = (unsigned*)((char*)d_ws + ((size_t)4 * BH2 * sizeof(short)));

  a0_gemm<<<2048, 256, 0, stream>>>(x, Wih0, bih0, bhh0, outs, flags);
  rnn_rec<<<NBLK, 512, 0, stream>>>(Whh0, Wih1, bih1, Whh1, bhh1, outs,
                                    h0hi, h0lo, h1hi, h1lo, flags);
}

// Round 8
// 5454.741 us; speedup vs baseline: 2.4162x; 2.4162x over previous
//
#include <hip/hip_runtime.h>
#include <hip/hip_bf16.h>

#define RNN_B 64
#define RNN_S 512
#define RNN_H 1024
#define BH (RNN_B * RNN_H)
#define L0_NB 16              // 64 cols of Whh0 each
#define L1_NB 32              // 32 cols of Wih1+Whh1 each
#define NBLK (L0_NB + L1_NB)  // 48 persistent blocks
#define FLAG_STRIDE 32
#define OUTS_ELEMS ((size_t)RNN_B * RNN_S * RNN_H)

typedef _Float16 f16;
typedef __attribute__((ext_vector_type(8))) _Float16 f16x8;
typedef __attribute__((ext_vector_type(8))) short bf16x8;
typedef __attribute__((ext_vector_type(4))) float f32x4;
typedef __attribute__((ext_vector_type(4))) int i32x4;

// raw buffer load, cachepolicy 17 = sc0|sc1: bypass L1/L2, read coherence point.
__device__ f32x4 __rnn_rawbufload_x4(i32x4 srsrc, int voffset, int soffset,
                                     int cachepolicy) __asm("llvm.amdgcn.raw.buffer.load.v4f32");

__device__ __forceinline__ i32x4 make_srd(const void* p, unsigned bytes) {
  i32x4 r;
  r[0] = (int)(unsigned)(unsigned long long)p;
  r[1] = (int)((unsigned long long)p >> 32);
  r[2] = (int)bytes;
  r[3] = 0x00020000;
  return r;
}

__device__ __forceinline__ f16x8 ld_h(i32x4 srd, int byteoff) {
  union { f32x4 f; f16x8 h; } u;
  u.f = __rnn_rawbufload_x4(srd, byteoff, 0, 17);
  return u.h;
}

// 2B write-through store to the coherence point (proven in R5/R6)
__device__ __forceinline__ void st_sys_u16(void* p, unsigned v) {
  asm volatile("global_store_short %0, %1, off sc0 sc1" :: "v"(p), "v"(v) : "memory");
}

__device__ __forceinline__ unsigned f16bits(float f) {
  union { f16 h; unsigned short u; } v; v.h = (f16)f; return (unsigned)v.u;
}

__device__ __forceinline__ short f2bf(float f) {
  union { float f; unsigned u; } v; v.f = f;
  return (short)((v.u + 0x7FFFu + ((v.u >> 16) & 1u)) >> 16);
}
__device__ __forceinline__ float bf2f(short h) {
  union { unsigned u; float f; } v; v.u = ((unsigned)(unsigned short)h) << 16;
  return v.f;
}
__device__ __forceinline__ f32x4 mfma16b(bf16x8 a, bf16x8 b, f32x4 c) {
  return __builtin_amdgcn_mfma_f32_16x16x32_bf16(a, b, c, 0, 0, 0);
}
__device__ __forceinline__ f32x4 mfma16f(f16x8 a, f16x8 b, f32x4 c) {
  return __builtin_amdgcn_mfma_f32_16x16x32_f16(a, b, c, 0, 0, 0);
}
__device__ __forceinline__ void cvt8_hl(const float* f, bf16x8* hi, bf16x8* lo) {
  #pragma unroll
  for (int i = 0; i < 8; ++i) {
    short h = f2bf(f[i]);
    (*hi)[i] = h;
    (*lo)[i] = f2bf(f[i] - bf2f(h));
  }
}
__device__ __forceinline__ f16x8 cvt8f(const float* f) {
  f16x8 r;
  #pragma unroll
  for (int i = 0; i < 8; ++i) r[i] = (f16)f[i];
  return r;
}

// ---------- Kernel 1: A0 = x @ W_ih0^T + b_ih0 + b_hh0 (split-bf16 3-pass, ~fp32 accurate)
__global__ __launch_bounds__(256) void a0_gemm(
    const float* __restrict__ x, const float* __restrict__ Wih0,
    const float* __restrict__ bih0, const float* __restrict__ bhh0,
    float* __restrict__ A0, unsigned* __restrict__ flags)
{
  if (blockIdx.x == 0) {
    for (int i = threadIdx.x; i < NBLK * FLAG_STRIDE; i += 256)
      __hip_atomic_store(&flags[i], 0u, __ATOMIC_RELAXED, __HIP_MEMORY_SCOPE_SYSTEM);
  }
  const int bn = blockIdx.x & 7;
  const int bm = blockIdx.x >> 3;
  const int tid = threadIdx.x;
  const int lane = tid & 63;
  const int w = tid >> 6;
  const int wr = w >> 1, wc = w & 1;
  const int l15 = lane & 15, lq = lane >> 4;

  __shared__ short As[2][128][40];
  __shared__ short Bs[2][128][40];

  f32x4 acc[4][4] = {};

  const int sr = tid >> 1;
  const int sc = (tid & 1) << 4;
  const float* xp = x + (size_t)(bm * 128 + sr) * RNN_H + sc;
  const float* wp = Wih0 + (size_t)(bn * 128 + sr) * RNN_H + sc;

  for (int k0 = 0; k0 < RNN_H; k0 += 32) {
    float xa[16], wa[16];
    #pragma unroll
    for (int j = 0; j < 4; ++j) {
      *(float4*)&xa[j * 4] = *(const float4*)(xp + k0 + j * 4);
      *(float4*)&wa[j * 4] = *(const float4*)(wp + k0 + j * 4);
    }
    __syncthreads();
    bf16x8 h0, l0, h1, l1;
    cvt8_hl(&xa[0], &h0, &l0); cvt8_hl(&xa[8], &h1, &l1);
    *(bf16x8*)&As[0][sr][sc] = h0; *(bf16x8*)&As[1][sr][sc] = l0;
    *(bf16x8*)&As[0][sr][sc + 8] = h1; *(bf16x8*)&As[1][sr][sc + 8] = l1;
    cvt8_hl(&wa[0], &h0, &l0); cvt8_hl(&wa[8], &h1, &l1);
    *(bf16x8*)&Bs[0][sr][sc] = h0; *(bf16x8*)&Bs[1][sr][sc] = l0;
    *(bf16x8*)&Bs[0][sr][sc + 8] = h1; *(bf16x8*)&Bs[1][sr][sc + 8] = l1;
    __syncthreads();
    bf16x8 ah[4], al[4], bh[4], bl[4];
    #pragma unroll
    for (int i = 0; i < 4; ++i) {
      ah[i] = *(const bf16x8*)&As[0][wr * 64 + i * 16 + l15][lq * 8];
      al[i] = *(const bf16x8*)&As[1][wr * 64 + i * 16 + l15][lq * 8];
    }
    #pragma unroll
    for (int j = 0; j < 4; ++j) {
      bh[j] = *(const bf16x8*)&Bs[0][wc * 64 + j * 16 + l15][lq * 8];
      bl[j] = *(const bf16x8*)&Bs[1][wc * 64 + j * 16 + l15][lq * 8];
    }
    #pragma unroll
    for (int i = 0; i < 4; ++i)
      #pragma unroll
      for (int j = 0; j < 4; ++j) {
        acc[i][j] = mfma16b(ah[i], bh[j], acc[i][j]);
        acc[i][j] = mfma16b(al[i], bh[j], acc[i][j]);
        acc[i][j] = mfma16b(ah[i], bl[j], acc[i][j]);
      }
  }

  #pragma unroll
  for (int j = 0; j < 4; ++j) {
    const int col = bn * 128 + wc * 64 + j * 16 + l15;
    const float bias = bih0[col] + bhh0[col];
    #pragma unroll
    for (int i = 0; i < 4; ++i) {
      const int row0 = bm * 128 + wr * 64 + i * 16 + lq * 4;
      #pragma unroll
      for (int r = 0; r < 4; ++r)
        A0[(size_t)(row0 + r) * RNN_H + col] = acc[i][j][r] + bias;
    }
  }
}

// ---------- grid barrier: flag store + poll, all sc0/sc1, no cache maintenance
__device__ __forceinline__ void gbar(unsigned* flags, unsigned target, int bid) {
  asm volatile("s_waitcnt vmcnt(0)" ::: "memory");
  __syncthreads();
  if (threadIdx.x == 0)
    __hip_atomic_store(&flags[bid * FLAG_STRIDE], target,
                       __ATOMIC_RELAXED, __HIP_MEMORY_SCOPE_SYSTEM);
  if (threadIdx.x < 64) {
    const unsigned* f = &flags[(threadIdx.x < NBLK ? threadIdx.x : 0) * FLAG_STRIDE];
    while (!__all(__hip_atomic_load(f, __ATOMIC_RELAXED,
                                    __HIP_MEMORY_SCOPE_SYSTEM) >= target))
      __builtin_amdgcn_s_sleep(1);
  }
  __syncthreads();
}

// ---------- Kernel 2: persistent layer-split recurrence, fp16 h, fp16 weights in LDS.
// blocks 0..15: layer 0, 64 cols each. blocks 16..47: layer 1, 32 cols each.
// 256 threads = 4 waves, each wave owns 16 batch rows x all block cols.
// Micro-structure = proven R5 pattern: direct mfma(ld_h(...)), scalar sc0/sc1 h-stores.
__global__ __launch_bounds__(256) void rnn_rec(
    const float* __restrict__ Whh0,
    const float* __restrict__ Wih1, const float* __restrict__ bih1,
    const float* __restrict__ Whh1, const float* __restrict__ bhh1,
    float* outs,             // d_out: A0 (read), layer-1 outs (write), hT tail
    f16* __restrict__ h0buf, // ws: [2][B][H] fp16 ping-pong
    f16* __restrict__ h1buf, // ws: [2][B][H] fp16 ping-pong
    unsigned* flags)
{
  const int bid = blockIdx.x;
  const bool isL0 = bid < L0_NB;
  const int tid = threadIdx.x;
  const int w = tid >> 6;
  const int lane = tid & 63;
  const int l15 = lane & 15;
  const int lq = lane >> 4;
  const int mt = w * 16;
  const int swz = l15 & 7;

  const i32x4 srd_h0 = make_srd(h0buf, 2u * BH * 2u);
  const i32x4 srd_h1 = make_srd(h1buf, 2u * BH * 2u);

  __shared__ __align__(16) f16 Ws[2 * 32 * RNN_H];     // 128 KiB weights (fp16, swizzled)

  // ---- stage weights fp32 -> fp16 into LDS, 16B-chunk swizzle: chunk c of row n -> c^(n&7)
  if (isL0) {
    const int n0s = bid * 64;
    const int n = tid >> 2;             // 0..63
    const int kb = (tid & 3) * 256;     // 4 threads/row
    const float* src = Whh0 + (size_t)(n0s + n) * RNN_H + kb;
    f16* dst = Ws + n * RNN_H;
    #pragma unroll 4
    for (int j = 0; j < 32; ++j) {
      float tmp[8];
      *(float4*)&tmp[0] = *(const float4*)(src + j * 8);
      *(float4*)&tmp[4] = *(const float4*)(src + j * 8 + 4);
      const int c = (kb >> 3) + j;
      *(f16x8*)&dst[((c ^ (n & 7)) << 3)] = cvt8f(tmp);
    }
  } else {
    const int n0s = (bid - L0_NB) * 32;
    const int n = tid >> 3;             // 0..31
    const int kb = (tid & 7) * 128;     // 8 threads/row
    #pragma unroll
    for (int m = 0; m < 2; ++m) {
      const float* src = (m ? Whh1 : Wih1) + (size_t)(n0s + n) * RNN_H + kb;
      f16* dst = Ws + m * 32 * RNN_H + n * RNN_H;
      #pragma unroll 4
      for (int j = 0; j < 16; ++j) {
        float tmp[8];
        *(float4*)&tmp[0] = *(const float4*)(src + j * 8);
        *(float4*)&tmp[4] = *(const float4*)(src + j * 8 + 4);
        const int c = (kb >> 3) + j;
        *(f16x8*)&dst[((c ^ (n & 7)) << 3)] = cvt8f(tmp);
      }
    }
  }

  float* hT = outs + OUTS_ELEMS;
  const int n0 = isL0 ? bid * 64 : (bid - L0_NB) * 32;
  float bias1v[2];
  if (!isL0) {
    #pragma unroll
    for (int ct = 0; ct < 2; ++ct)
      bias1v[ct] = bih1[n0 + ct * 16 + l15] + bhh1[n0 + ct * 16 + l15];
  }
  __syncthreads();

  float a0v[16];
  if (isL0) {
    #pragma unroll
    for (int ct = 0; ct < 4; ++ct)
      #pragma unroll
      for (int r = 0; r < 4; ++r)
        a0v[ct * 4 + r] = outs[((size_t)(mt + lq * 4 + r) * RNN_S + 0) * RNN_H + n0 + ct * 16 + l15];
  }

  for (int p = 0; p <= RNN_S; ++p) {
    if (isL0) {
      if (p < RNN_S) {
        // h0(p) = tanh(A0[:,p,:] + h0(p-1) @ Whh0^T), cols n0..n0+64
        f32x4 acc[4];
        #pragma unroll
        for (int ct = 0; ct < 4; ++ct) {
          acc[ct][0] = a0v[ct * 4 + 0]; acc[ct][1] = a0v[ct * 4 + 1];
          acc[ct][2] = a0v[ct * 4 + 2]; acc[ct][3] = a0v[ct * 4 + 3];
        }
        if (p > 0) {
          const int hb = (((p - 1) & 1) * BH + (mt + l15) * RNN_H + lq * 8) * 2;
          #pragma unroll
          for (int ks = 0; ks < 32; ++ks) {
            f16x8 hx = ld_h(srd_h0, hb + ks * 64);
            const int c = (((ks * 4 + lq) ^ swz) << 3);
            #pragma unroll
            for (int ct = 0; ct < 4; ++ct)
              acc[ct] = mfma16f(hx, *(const f16x8*)&Ws[(ct * 16 + l15) * RNN_H + c], acc[ct]);
          }
        }
        float vals[16];
        #pragma unroll
        for (int i = 0; i < 16; ++i) vals[i] = tanhf(acc[i >> 2][i & 3]);
        const size_t hd = (size_t)(p & 1) * BH;
        #pragma unroll
        for (int ct = 0; ct < 4; ++ct)
          #pragma unroll
          for (int r = 0; r < 4; ++r)
            st_sys_u16(&h0buf[hd + (size_t)(mt + lq * 4 + r) * RNN_H + n0 + ct * 16 + l15],
                       f16bits(vals[ct * 4 + r]));
        if (p == RNN_S - 1) {
          #pragma unroll
          for (int ct = 0; ct < 4; ++ct)
            #pragma unroll
            for (int r = 0; r < 4; ++r)
              hT[(size_t)(mt + lq * 4 + r) * RNN_H + n0 + ct * 16 + l15] = vals[ct * 4 + r];
        }
        if (p + 1 < RNN_S) {
          #pragma unroll
          for (int ct = 0; ct < 4; ++ct)
            #pragma unroll
            for (int r = 0; r < 4; ++r)
              a0v[ct * 4 + r] = outs[((size_t)(mt + lq * 4 + r) * RNN_S + (p + 1)) * RNN_H + n0 + ct * 16 + l15];
        }
      }
    } else {
      if (p >= 1) {
        // t = p-1: h1(t) = tanh(b1 + h0(t) @ Wih1^T + h1(t-1) @ Whh1^T), cols n0..n0+32
        const int t = p - 1;
        f32x4 acc0[2], acc1[2];
        #pragma unroll
        for (int ct = 0; ct < 2; ++ct) {
          acc0[ct][0] = bias1v[ct]; acc0[ct][1] = bias1v[ct];
          acc0[ct][2] = bias1v[ct]; acc0[ct][3] = bias1v[ct];
          acc1[ct][0] = 0.f; acc1[ct][1] = 0.f; acc1[ct][2] = 0.f; acc1[ct][3] = 0.f;
        }
        const int hb0 = ((t & 1) * BH + (mt + l15) * RNN_H + lq * 8) * 2;
        if (t > 0) {
          const int hb1 = (((t - 1) & 1) * BH + (mt + l15) * RNN_H + lq * 8) * 2;
          #pragma unroll
          for (int ks = 0; ks < 32; ++ks) {
            f16x8 hx = ld_h(srd_h0, hb0 + ks * 64);
            f16x8 gx = ld_h(srd_h1, hb1 + ks * 64);
            const int c = (((ks * 4 + lq) ^ swz) << 3);
            #pragma unroll
            for (int ct = 0; ct < 2; ++ct) {
              acc0[ct] = mfma16f(hx, *(const f16x8*)&Ws[(ct * 16 + l15) * RNN_H + c], acc0[ct]);
              acc1[ct] = mfma16f(gx, *(const f16x8*)&Ws[32 * RNN_H + (ct * 16 + l15) * RNN_H + c], acc1[ct]);
            }
          }
        } else {
          #pragma unroll
          for (int ks = 0; ks < 32; ++ks) {
            f16x8 hx = ld_h(srd_h0, hb0 + ks * 64);
            const int c = (((ks * 4 + lq) ^ swz) << 3);
            #pragma unroll
            for (int ct = 0; ct < 2; ++ct)
              acc0[ct] = mfma16f(hx, *(const f16x8*)&Ws[(ct * 16 + l15) * RNN_H + c], acc0[ct]);
          }
        }
        float vals[8];
        #pragma unroll
        for (int ct = 0; ct < 2; ++ct) {
          f32x4 s = acc0[ct] + acc1[ct];
          #pragma unroll
          for (int r = 0; r < 4; ++r) vals[ct * 4 + r] = tanhf(s[r]);
        }
        const size_t hd = (size_t)(t & 1) * BH;
        #pragma unroll
        for (int ct = 0; ct < 2; ++ct)
          #pragma unroll
          for (int r = 0; r < 4; ++r) {
            const int b = mt + lq * 4 + r;
            st_sys_u16(&h1buf[hd + (size_t)b * RNN_H + n0 + ct * 16 + l15],
                       f16bits(vals[ct * 4 + r]));
            outs[((size_t)b * RNN_S + t) * RNN_H + n0 + ct * 16 + l15] = vals[ct * 4 + r];
          }
        if (t == RNN_S - 1) {
          #pragma unroll
          for (int ct = 0; ct < 2; ++ct)
            #pragma unroll
            for (int r = 0; r < 4; ++r)
              hT[(size_t)BH + (size_t)(mt + lq * 4 + r) * RNN_H + n0 + ct * 16 + l15] = vals[ct * 4 + r];
        }
      }
    }
    if (p < RNN_S) gbar(flags, (unsigned)(p + 1), bid);
  }
}

extern "C" void kernel_launch(void* const* d_in, const int* in_sizes, int n_in,
                              void* d_out, int out_size, void* d_ws, size_t ws_size,
                              hipStream_t stream) {
  const float* x    = (const float*)d_in[0];
  const float* Wih0 = (const float*)d_in[1];
  const float* bih0 = (const float*)d_in[2];
  const float* Whh0 = (const float*)d_in[3];
  const float* bhh0 = (const float*)d_in[4];
  const float* Wih1 = (const float*)d_in[5];
  const float* bih1 = (const float*)d_in[6];
  const float* Whh1 = (const float*)d_in[7];
  const float* bhh1 = (const float*)d_in[8];
  float* outs = (float*)d_out;

  f16* h0buf = (f16*)d_ws;                          // 2*64*1024 fp16 = 256 KiB
  f16* h1buf = h0buf + 2 * BH;                      // 256 KiB
  unsigned* flags = (unsigned*)((char*)d_ws + (1u << 19));  // at +512 KiB

  a0_gemm<<<2048, 256, 0, stream>>>(x, Wih0, bih0, bhh0, outs, flags);
  rnn_rec<<<NBLK, 256, 0, stream>>>(Whh0, Wih1, bih1, Whh1, bhh1, outs,
                                    h0buf, h1buf, flags);
}

// Round 9
// 2997.545 us; speedup vs baseline: 4.3968x; 1.8197x over previous
//
#include <hip/hip_runtime.h>
#include <hip/hip_bf16.h>

#define RNN_B 64
#define RNN_S 512
#define RNN_H 1024
#define BH (RNN_B * RNN_H)
#define L0_NBLK 64            // 16 col-slices x 4 batch-slices (64 cols x 16 rows each)
#define L1_NBLK 128           // 32 col-slices x 4 batch-slices (32 cols x 16 rows each)
#define NBLK (L0_NBLK + L1_NBLK)
#define FLAG_STRIDE 32
#define OUTS_ELEMS ((size_t)RNN_B * RNN_S * RNN_H)

typedef _Float16 f16;
typedef __attribute__((ext_vector_type(8))) _Float16 f16x8;
typedef __attribute__((ext_vector_type(8))) short bf16x8;
typedef __attribute__((ext_vector_type(4))) float f32x4;
typedef __attribute__((ext_vector_type(4))) int i32x4;

// raw buffer load, cachepolicy 17 = sc0|sc1: bypass L1/L2, read coherence point.
__device__ f32x4 __rnn_rawbufload_x4(i32x4 srsrc, int voffset, int soffset,
                                     int cachepolicy) __asm("llvm.amdgcn.raw.buffer.load.v4f32");

__device__ __forceinline__ i32x4 make_srd(const void* p, unsigned bytes) {
  i32x4 r;
  r[0] = (int)(unsigned)(unsigned long long)p;
  r[1] = (int)((unsigned long long)p >> 32);
  r[2] = (int)bytes;
  r[3] = 0x00020000;
  return r;
}

__device__ __forceinline__ f16x8 ld_h(i32x4 srd, int byteoff) {
  union { f32x4 f; f16x8 h; } u;
  u.f = __rnn_rawbufload_x4(srd, byteoff, 0, 17);
  return u.h;
}

// 2B write-through store to the coherence point (proven R5-R8)
__device__ __forceinline__ void st_sys_u16(void* p, unsigned v) {
  asm volatile("global_store_short %0, %1, off sc0 sc1" :: "v"(p), "v"(v) : "memory");
}

__device__ __forceinline__ unsigned f16bits(float f) {
  union { f16 h; unsigned short u; } v; v.h = (f16)f; return (unsigned)v.u;
}
__device__ __forceinline__ short f2bf(float f) {
  union { float f; unsigned u; } v; v.f = f;
  return (short)((v.u + 0x7FFFu + ((v.u >> 16) & 1u)) >> 16);
}
__device__ __forceinline__ float bf2f(short h) {
  union { unsigned u; float f; } v; v.u = ((unsigned)(unsigned short)h) << 16;
  return v.f;
}
__device__ __forceinline__ f32x4 mfma16b(bf16x8 a, bf16x8 b, f32x4 c) {
  return __builtin_amdgcn_mfma_f32_16x16x32_bf16(a, b, c, 0, 0, 0);
}
__device__ __forceinline__ f32x4 mfma16f(f16x8 a, f16x8 b, f32x4 c) {
  return __builtin_amdgcn_mfma_f32_16x16x32_f16(a, b, c, 0, 0, 0);
}
__device__ __forceinline__ void cvt8_hl(const float* f, bf16x8* hi, bf16x8* lo) {
  #pragma unroll
  for (int i = 0; i < 8; ++i) {
    short h = f2bf(f[i]);
    (*hi)[i] = h;
    (*lo)[i] = f2bf(f[i] - bf2f(h));
  }
}
__device__ __forceinline__ f16x8 cvt8f(const float* f) {
  f16x8 r;
  #pragma unroll
  for (int i = 0; i < 8; ++i) r[i] = (f16)f[i];
  return r;
}

// ---------- Kernel 1: A0 = x @ W_ih0^T + b_ih0 + b_hh0 (split-bf16 3-pass, ~fp32 accurate)
__global__ __launch_bounds__(256) void a0_gemm(
    const float* __restrict__ x, const float* __restrict__ Wih0,
    const float* __restrict__ bih0, const float* __restrict__ bhh0,
    float* __restrict__ A0, unsigned* __restrict__ flags)
{
  if (blockIdx.x == 0) {
    for (int i = threadIdx.x; i < NBLK * FLAG_STRIDE; i += 256)
      __hip_atomic_store(&flags[i], 0u, __ATOMIC_RELAXED, __HIP_MEMORY_SCOPE_SYSTEM);
  }
  const int bn = blockIdx.x & 7;
  const int bm = blockIdx.x >> 3;
  const int tid = threadIdx.x;
  const int lane = tid & 63;
  const int w = tid >> 6;
  const int wr = w >> 1, wc = w & 1;
  const int l15 = lane & 15, lq = lane >> 4;

  __shared__ short As[2][128][40];
  __shared__ short Bs[2][128][40];

  f32x4 acc[4][4] = {};

  const int sr = tid >> 1;
  const int sc = (tid & 1) << 4;
  const float* xp = x + (size_t)(bm * 128 + sr) * RNN_H + sc;
  const float* wp = Wih0 + (size_t)(bn * 128 + sr) * RNN_H + sc;

  for (int k0 = 0; k0 < RNN_H; k0 += 32) {
    float xa[16], wa[16];
    #pragma unroll
    for (int j = 0; j < 4; ++j) {
      *(float4*)&xa[j * 4] = *(const float4*)(xp + k0 + j * 4);
      *(float4*)&wa[j * 4] = *(const float4*)(wp + k0 + j * 4);
    }
    __syncthreads();
    bf16x8 h0, l0, h1, l1;
    cvt8_hl(&xa[0], &h0, &l0); cvt8_hl(&xa[8], &h1, &l1);
    *(bf16x8*)&As[0][sr][sc] = h0; *(bf16x8*)&As[1][sr][sc] = l0;
    *(bf16x8*)&As[0][sr][sc + 8] = h1; *(bf16x8*)&As[1][sr][sc + 8] = l1;
    cvt8_hl(&wa[0], &h0, &l0); cvt8_hl(&wa[8], &h1, &l1);
    *(bf16x8*)&Bs[0][sr][sc] = h0; *(bf16x8*)&Bs[1][sr][sc] = l0;
    *(bf16x8*)&Bs[0][sr][sc + 8] = h1; *(bf16x8*)&Bs[1][sr][sc + 8] = l1;
    __syncthreads();
    bf16x8 ah[4], al[4], bh[4], bl[4];
    #pragma unroll
    for (int i = 0; i < 4; ++i) {
      ah[i] = *(const bf16x8*)&As[0][wr * 64 + i * 16 + l15][lq * 8];
      al[i] = *(const bf16x8*)&As[1][wr * 64 + i * 16 + l15][lq * 8];
    }
    #pragma unroll
    for (int j = 0; j < 4; ++j) {
      bh[j] = *(const bf16x8*)&Bs[0][wc * 64 + j * 16 + l15][lq * 8];
      bl[j] = *(const bf16x8*)&Bs[1][wc * 64 + j * 16 + l15][lq * 8];
    }
    #pragma unroll
    for (int i = 0; i < 4; ++i)
      #pragma unroll
      for (int j = 0; j < 4; ++j) {
        acc[i][j] = mfma16b(ah[i], bh[j], acc[i][j]);
        acc[i][j] = mfma16b(al[i], bh[j], acc[i][j]);
        acc[i][j] = mfma16b(ah[i], bl[j], acc[i][j]);
      }
  }

  #pragma unroll
  for (int j = 0; j < 4; ++j) {
    const int col = bn * 128 + wc * 64 + j * 16 + l15;
    const float bias = bih0[col] + bhh0[col];
    #pragma unroll
    for (int i = 0; i < 4; ++i) {
      const int row0 = bm * 128 + wr * 64 + i * 16 + lq * 4;
      #pragma unroll
      for (int r = 0; r < 4; ++r)
        A0[(size_t)(row0 + r) * RNN_H + col] = acc[i][j][r] + bias;
    }
  }
}

// ---------- grid barrier: flag store + 192-flag poll (3 per lane), all sc0/sc1
__device__ __forceinline__ void gbar(unsigned* flags, unsigned target, int bid) {
  asm volatile("s_waitcnt vmcnt(0)" ::: "memory");
  __syncthreads();
  if (threadIdx.x == 0)
    __hip_atomic_store(&flags[bid * FLAG_STRIDE], target,
                       __ATOMIC_RELAXED, __HIP_MEMORY_SCOPE_SYSTEM);
  if (threadIdx.x < 64) {
    const unsigned* f0 = &flags[threadIdx.x * FLAG_STRIDE];
    const unsigned* f1 = &flags[(threadIdx.x + 64) * FLAG_STRIDE];
    const unsigned* f2 = &flags[(threadIdx.x + 128) * FLAG_STRIDE];
    for (;;) {
      bool ok = __hip_atomic_load(f0, __ATOMIC_RELAXED, __HIP_MEMORY_SCOPE_SYSTEM) >= target
             && __hip_atomic_load(f1, __ATOMIC_RELAXED, __HIP_MEMORY_SCOPE_SYSTEM) >= target
             && __hip_atomic_load(f2, __ATOMIC_RELAXED, __HIP_MEMORY_SCOPE_SYSTEM) >= target;
      if (__all(ok)) break;
      __builtin_amdgcn_s_sleep(1);
    }
  }
  __syncthreads();
}

// ---------- Kernel 2: persistent recurrence, batch-split x4 + K-split x4.
// blocks 0..63: layer 0 — bs=bid>>4 (16 rows), cs=bid&15 (64 cols).
// blocks 64..191: layer 1 — bs=(bid-64)>>5, cs=(bid-64)&31 (32 cols).
// 4 waves = 4 K-slices of 256; partials reduced via LDS red[4][16][64].
__global__ __launch_bounds__(256) void rnn_rec(
    const float* __restrict__ Whh0,
    const float* __restrict__ Wih1, const float* __restrict__ bih1,
    const float* __restrict__ Whh1, const float* __restrict__ bhh1,
    float* outs,             // d_out: A0 (read), layer-1 outs (write), hT tail
    f16* __restrict__ h0buf, // ws: [2][B][H] fp16 ping-pong
    f16* __restrict__ h1buf, // ws: [2][B][H] fp16 ping-pong
    unsigned* flags)
{
  const int bid = blockIdx.x;
  const bool isL0 = bid < L0_NBLK;
  const int tid = threadIdx.x;
  const int w = tid >> 6;         // K-slice 0..3 (256 elems each)
  const int lane = tid & 63;
  const int l15 = lane & 15;
  const int lq = lane >> 4;
  const int swz = l15 & 7;

  int b0, n0;
  if (isL0) { b0 = (bid >> 4) * 16; n0 = (bid & 15) * 64; }
  else { const int b2 = bid - L0_NBLK; b0 = (b2 >> 5) * 16; n0 = (b2 & 31) * 32; }

  const i32x4 srd_h0 = make_srd(h0buf, 2u * BH * 2u);
  const i32x4 srd_h1 = make_srd(h1buf, 2u * BH * 2u);

  __shared__ __align__(16) f16 Ws[2 * 32 * RNN_H];   // 128 KiB weights (fp16, swizzled)
  __shared__ float red[4][16][64];                    // 16 KiB K-split reduction

  // ---- stage weights fp32 -> fp16 into LDS, 16B-chunk swizzle: chunk c of row n -> c^(n&7)
  if (isL0) {
    const int n = tid >> 2;             // 0..63
    const int kb = (tid & 3) * 256;
    const float* src = Whh0 + (size_t)(n0 + n) * RNN_H + kb;
    f16* dst = Ws + n * RNN_H;
    #pragma unroll 4
    for (int j = 0; j < 32; ++j) {
      float tmp[8];
      *(float4*)&tmp[0] = *(const float4*)(src + j * 8);
      *(float4*)&tmp[4] = *(const float4*)(src + j * 8 + 4);
      const int c = (kb >> 3) + j;
      *(f16x8*)&dst[((c ^ (n & 7)) << 3)] = cvt8f(tmp);
    }
  } else {
    const int n = tid >> 3;             // 0..31
    const int kb = (tid & 7) * 128;
    #pragma unroll
    for (int m = 0; m < 2; ++m) {
      const float* src = (m ? Whh1 : Wih1) + (size_t)(n0 + n) * RNN_H + kb;
      f16* dst = Ws + m * 32 * RNN_H + n * RNN_H;
      #pragma unroll 4
      for (int j = 0; j < 16; ++j) {
        float tmp[8];
        *(float4*)&tmp[0] = *(const float4*)(src + j * 8);
        *(float4*)&tmp[4] = *(const float4*)(src + j * 8 + 4);
        const int c = (kb >> 3) + j;
        *(f16x8*)&dst[((c ^ (n & 7)) << 3)] = cvt8f(tmp);
      }
    }
  }

  float* hT = outs + OUTS_ELEMS;

  // combine-phase role
  int ccol, crg;
  float bias1s = 0.f;
  if (isL0) { ccol = tid & 63; crg = tid >> 6; }        // rows crg*4 + r
  else      { ccol = tid & 31; crg = tid >> 5;          // rows crg*2 + r
              bias1s = bih1[n0 + ccol] + bhh1[n0 + ccol]; }
  __syncthreads();

  float a0v[4];
  if (isL0) {
    #pragma unroll
    for (int r = 0; r < 4; ++r)
      a0v[r] = outs[((size_t)(b0 + crg * 4 + r) * RNN_S + 0) * RNN_H + n0 + ccol];
  }

  for (int p = 0; p <= RNN_S; ++p) {
    if (isL0) {
      if (p < RNN_S) {
        if (p > 0) {
          const int hb = (((p - 1) & 1) * BH + (b0 + l15) * RNN_H + w * 256 + lq * 8) * 2;
          f32x4 acc[4] = {};
          #pragma unroll
          for (int ks = 0; ks < 8; ++ks) {
            f16x8 hx = ld_h(srd_h0, hb + ks * 64);
            const int c = ((w * 32 + ks * 4 + lq) ^ swz) << 3;
            #pragma unroll
            for (int ct = 0; ct < 4; ++ct)
              acc[ct] = mfma16f(hx, *(const f16x8*)&Ws[(ct * 16 + l15) * RNN_H + c], acc[ct]);
          }
          #pragma unroll
          for (int ct = 0; ct < 4; ++ct)
            #pragma unroll
            for (int r = 0; r < 4; ++r)
              red[w][lq * 4 + r][ct * 16 + l15] = acc[ct][r];
        }
        __syncthreads();
        float vals[4];
        #pragma unroll
        for (int r = 0; r < 4; ++r) {
          const int row = crg * 4 + r;
          float s = a0v[r];
          if (p > 0)
            s += red[0][row][ccol] + red[1][row][ccol] + red[2][row][ccol] + red[3][row][ccol];
          vals[r] = tanhf(s);
          st_sys_u16(&h0buf[(size_t)(p & 1) * BH + (size_t)(b0 + row) * RNN_H + n0 + ccol],
                     f16bits(vals[r]));
        }
        if (p == RNN_S - 1) {
          #pragma unroll
          for (int r = 0; r < 4; ++r)
            hT[(size_t)(b0 + crg * 4 + r) * RNN_H + n0 + ccol] = vals[r];
        }
        if (p + 1 < RNN_S) {
          #pragma unroll
          for (int r = 0; r < 4; ++r)
            a0v[r] = outs[((size_t)(b0 + crg * 4 + r) * RNN_S + (p + 1)) * RNN_H + n0 + ccol];
        }
      }
    } else {
      if (p >= 1) {
        const int t = p - 1;
        const int hb0 = ((t & 1) * BH + (b0 + l15) * RNN_H + w * 256 + lq * 8) * 2;
        f32x4 acc[2] = {};
        if (t > 0) {
          const int hb1 = (((t - 1) & 1) * BH + (b0 + l15) * RNN_H + w * 256 + lq * 8) * 2;
          #pragma unroll
          for (int ks = 0; ks < 8; ++ks) {
            f16x8 hx = ld_h(srd_h0, hb0 + ks * 64);
            f16x8 gx = ld_h(srd_h1, hb1 + ks * 64);
            const int c = ((w * 32 + ks * 4 + lq) ^ swz) << 3;
            #pragma unroll
            for (int ct = 0; ct < 2; ++ct) {
              acc[ct] = mfma16f(hx, *(const f16x8*)&Ws[(ct * 16 + l15) * RNN_H + c], acc[ct]);
              acc[ct] = mfma16f(gx, *(const f16x8*)&Ws[32 * RNN_H + (ct * 16 + l15) * RNN_H + c], acc[ct]);
            }
          }
        } else {
          #pragma unroll
          for (int ks = 0; ks < 8; ++ks) {
            f16x8 hx = ld_h(srd_h0, hb0 + ks * 64);
            const int c = ((w * 32 + ks * 4 + lq) ^ swz) << 3;
            #pragma unroll
            for (int ct = 0; ct < 2; ++ct)
              acc[ct] = mfma16f(hx, *(const f16x8*)&Ws[(ct * 16 + l15) * RNN_H + c], acc[ct]);
          }
        }
        #pragma unroll
        for (int ct = 0; ct < 2; ++ct)
          #pragma unroll
          for (int r = 0; r < 4; ++r)
            red[w][lq * 4 + r][ct * 16 + l15] = acc[ct][r];
        __syncthreads();
        #pragma unroll
        for (int r = 0; r < 2; ++r) {
          const int row = crg * 2 + r;
          float s = bias1s + red[0][row][ccol] + red[1][row][ccol]
                           + red[2][row][ccol] + red[3][row][ccol];
          const float v = tanhf(s);
          st_sys_u16(&h1buf[(size_t)(t & 1) * BH + (size_t)(b0 + row) * RNN_H + n0 + ccol],
                     f16bits(v));
          outs[((size_t)(b0 + row) * RNN_S + t) * RNN_H + n0 + ccol] = v;
          if (t == RNN_S - 1)
            hT[(size_t)BH + (size_t)(b0 + row) * RNN_H + n0 + ccol] = v;
        }
      }
    }
    if (p < RNN_S) gbar(flags, (unsigned)(p + 1), bid);
  }
}

extern "C" void kernel_launch(void* const* d_in, const int* in_sizes, int n_in,
                              void* d_out, int out_size, void* d_ws, size_t ws_size,
                              hipStream_t stream) {
  const float* x    = (const float*)d_in[0];
  const float* Wih0 = (const float*)d_in[1];
  const float* bih0 = (const float*)d_in[2];
  const float* Whh0 = (const float*)d_in[3];
  const float* bhh0 = (const float*)d_in[4];
  const float* Wih1 = (const float*)d_in[5];
  const float* bih1 = (const float*)d_in[6];
  const float* Whh1 = (const float*)d_in[7];
  const float* bhh1 = (const float*)d_in[8];
  float* outs = (float*)d_out;

  f16* h0buf = (f16*)d_ws;                          // 2*64*1024 fp16 = 256 KiB
  f16* h1buf = h0buf + 2 * BH;                      // 256 KiB
  unsigned* flags = (unsigned*)((char*)d_ws + (1u << 19));  // at +512 KiB (24 KiB used)

  a0_gemm<<<2048, 256, 0, stream>>>(x, Wih0, bih0, bhh0, outs, flags);
  rnn_rec<<<NBLK, 256, 0, stream>>>(Whh0, Wih1, bih1, Whh1, bhh1, outs,
                                    h0buf, h1buf, flags);
}

// Round 10
// 2610.745 us; speedup vs baseline: 5.0482x; 1.1482x over previous
//
#include <hip/hip_runtime.h>
#include <hip/hip_bf16.h>

#define RNN_B 64
#define RNN_S 512
#define RNN_H 1024
#define BH (RNN_B * RNN_H)
#define L0_NBLK 64            // 16 col-slices x 4 batch-slices (64 cols x 16 rows each)
#define L1_NBLK 128           // 32 col-slices x 4 batch-slices (32 cols x 16 rows each)
#define NBLK (L0_NBLK + L1_NBLK)
#define NFLAGS 192            // 4 domains x 48 flags
#define FLAG_STRIDE 32
#define OUTS_ELEMS ((size_t)RNN_B * RNN_S * RNN_H)

typedef _Float16 f16;
typedef __attribute__((ext_vector_type(8))) _Float16 f16x8;
typedef __attribute__((ext_vector_type(8))) short bf16x8;
typedef __attribute__((ext_vector_type(4))) float f32x4;
typedef __attribute__((ext_vector_type(4))) int i32x4;

// raw buffer load, cachepolicy 17 = sc0|sc1: bypass L1/L2, read coherence point.
__device__ f32x4 __rnn_rawbufload_x4(i32x4 srsrc, int voffset, int soffset,
                                     int cachepolicy) __asm("llvm.amdgcn.raw.buffer.load.v4f32");

__device__ __forceinline__ i32x4 make_srd(const void* p, unsigned bytes) {
  i32x4 r;
  r[0] = (int)(unsigned)(unsigned long long)p;
  r[1] = (int)((unsigned long long)p >> 32);
  r[2] = (int)bytes;
  r[3] = 0x00020000;
  return r;
}

__device__ __forceinline__ f16x8 ld_h(i32x4 srd, int byteoff) {
  union { f32x4 f; f16x8 h; } u;
  u.f = __rnn_rawbufload_x4(srd, byteoff, 0, 17);
  return u.h;
}

// 2B write-through store to the coherence point (proven R5-R9)
__device__ __forceinline__ void st_sys_u16(void* p, unsigned v) {
  asm volatile("global_store_short %0, %1, off sc0 sc1" :: "v"(p), "v"(v) : "memory");
}

__device__ __forceinline__ unsigned f16bits(float f) {
  union { f16 h; unsigned short u; } v; v.h = (f16)f; return (unsigned)v.u;
}
__device__ __forceinline__ short f2bf(float f) {
  union { float f; unsigned u; } v; v.f = f;
  return (short)((v.u + 0x7FFFu + ((v.u >> 16) & 1u)) >> 16);
}
__device__ __forceinline__ float bf2f(short h) {
  union { unsigned u; float f; } v; v.u = ((unsigned)(unsigned short)h) << 16;
  return v.f;
}
__device__ __forceinline__ f32x4 mfma16b(bf16x8 a, bf16x8 b, f32x4 c) {
  return __builtin_amdgcn_mfma_f32_16x16x32_bf16(a, b, c, 0, 0, 0);
}
__device__ __forceinline__ f32x4 mfma16f(f16x8 a, f16x8 b, f32x4 c) {
  return __builtin_amdgcn_mfma_f32_16x16x32_f16(a, b, c, 0, 0, 0);
}
__device__ __forceinline__ void cvt8_hl(const float* f, bf16x8* hi, bf16x8* lo) {
  #pragma unroll
  for (int i = 0; i < 8; ++i) {
    short h = f2bf(f[i]);
    (*hi)[i] = h;
    (*lo)[i] = f2bf(f[i] - bf2f(h));
  }
}
__device__ __forceinline__ f16x8 cvt8f(const float* f) {
  f16x8 r;
  #pragma unroll
  for (int i = 0; i < 8; ++i) r[i] = (f16)f[i];
  return r;
}

// ---------- Kernel 1: A0 = x @ W_ih0^T + b_ih0 + b_hh0 (split-bf16 3-pass, ~fp32 accurate)
__global__ __launch_bounds__(256) void a0_gemm(
    const float* __restrict__ x, const float* __restrict__ Wih0,
    const float* __restrict__ bih0, const float* __restrict__ bhh0,
    float* __restrict__ A0, unsigned* __restrict__ flags)
{
  if (blockIdx.x == 0) {
    for (int i = threadIdx.x; i < NFLAGS * FLAG_STRIDE; i += 256)
      __hip_atomic_store(&flags[i], 0u, __ATOMIC_RELAXED, __HIP_MEMORY_SCOPE_SYSTEM);
  }
  const int bn = blockIdx.x & 7;
  const int bm = blockIdx.x >> 3;
  const int tid = threadIdx.x;
  const int lane = tid & 63;
  const int w = tid >> 6;
  const int wr = w >> 1, wc = w & 1;
  const int l15 = lane & 15, lq = lane >> 4;

  __shared__ short As[2][128][40];
  __shared__ short Bs[2][128][40];

  f32x4 acc[4][4] = {};

  const int sr = tid >> 1;
  const int sc = (tid & 1) << 4;
  const float* xp = x + (size_t)(bm * 128 + sr) * RNN_H + sc;
  const float* wp = Wih0 + (size_t)(bn * 128 + sr) * RNN_H + sc;

  for (int k0 = 0; k0 < RNN_H; k0 += 32) {
    float xa[16], wa[16];
    #pragma unroll
    for (int j = 0; j < 4; ++j) {
      *(float4*)&xa[j * 4] = *(const float4*)(xp + k0 + j * 4);
      *(float4*)&wa[j * 4] = *(const float4*)(wp + k0 + j * 4);
    }
    __syncthreads();
    bf16x8 h0, l0, h1, l1;
    cvt8_hl(&xa[0], &h0, &l0); cvt8_hl(&xa[8], &h1, &l1);
    *(bf16x8*)&As[0][sr][sc] = h0; *(bf16x8*)&As[1][sr][sc] = l0;
    *(bf16x8*)&As[0][sr][sc + 8] = h1; *(bf16x8*)&As[1][sr][sc + 8] = l1;
    cvt8_hl(&wa[0], &h0, &l0); cvt8_hl(&wa[8], &h1, &l1);
    *(bf16x8*)&Bs[0][sr][sc] = h0; *(bf16x8*)&Bs[1][sr][sc] = l0;
    *(bf16x8*)&Bs[0][sr][sc + 8] = h1; *(bf16x8*)&Bs[1][sr][sc + 8] = l1;
    __syncthreads();
    bf16x8 ah[4], al[4], bh[4], bl[4];
    #pragma unroll
    for (int i = 0; i < 4; ++i) {
      ah[i] = *(const bf16x8*)&As[0][wr * 64 + i * 16 + l15][lq * 8];
      al[i] = *(const bf16x8*)&As[1][wr * 64 + i * 16 + l15][lq * 8];
    }
    #pragma unroll
    for (int j = 0; j < 4; ++j) {
      bh[j] = *(const bf16x8*)&Bs[0][wc * 64 + j * 16 + l15][lq * 8];
      bl[j] = *(const bf16x8*)&Bs[1][wc * 64 + j * 16 + l15][lq * 8];
    }
    #pragma unroll
    for (int i = 0; i < 4; ++i)
      #pragma unroll
      for (int j = 0; j < 4; ++j) {
        acc[i][j] = mfma16b(ah[i], bh[j], acc[i][j]);
        acc[i][j] = mfma16b(al[i], bh[j], acc[i][j]);
        acc[i][j] = mfma16b(ah[i], bl[j], acc[i][j]);
      }
  }

  #pragma unroll
  for (int j = 0; j < 4; ++j) {
    const int col = bn * 128 + wc * 64 + j * 16 + l15;
    const float bias = bih0[col] + bhh0[col];
    #pragma unroll
    for (int i = 0; i < 4; ++i) {
      const int row0 = bm * 128 + wr * 64 + i * 16 + lq * 4;
      #pragma unroll
      for (int r = 0; r < 4; ++r)
        A0[(size_t)(row0 + r) * RNN_H + col] = acc[i][j][r] + bias;
    }
  }
}

// ---------- per-domain wait: lanes 0-15 poll L0 flags vs tL0, lanes 16-47 poll L1 flags vs tL1
__device__ __forceinline__ void waitflags(const unsigned* fbase, int tL0, int tL1) {
  if (threadIdx.x < 64) {
    const int l = threadIdx.x;
    const unsigned* f = fbase + (l < 48 ? l : 0) * FLAG_STRIDE;
    const int tgt = (l < 16) ? tL0 : (l < 48 ? tL1 : 0);
    while (!__all((int)__hip_atomic_load(f, __ATOMIC_RELAXED,
                                         __HIP_MEMORY_SCOPE_SYSTEM) >= tgt))
      __builtin_amdgcn_s_sleep(1);
  }
  __syncthreads();
}

// publish progress: drain h stores, block-arrive, store monotonic counter
__device__ __forceinline__ void publish(unsigned* slot, unsigned v) {
  asm volatile("s_waitcnt vmcnt(0)" ::: "memory");
  __syncthreads();
  if (threadIdx.x == 0)
    __hip_atomic_store(slot, v, __ATOMIC_RELAXED, __HIP_MEMORY_SCOPE_SYSTEM);
}

// ---------- Kernel 2: persistent recurrence, batch-split x4 + K-split x4,
// per-batch-slice producer/consumer flags, depth-D ping-pong (run-ahead D-1).
__global__ __launch_bounds__(256) void rnn_rec(
    const float* __restrict__ Whh0,
    const float* __restrict__ Wih1, const float* __restrict__ bih1,
    const float* __restrict__ Whh1, const float* __restrict__ bhh1,
    float* outs,             // d_out: A0 (read), layer-1 outs (write), hT tail
    f16* __restrict__ h0buf, // ws: [D][B][H] fp16 ring
    f16* __restrict__ h1buf, // ws: [D][B][H] fp16 ring
    unsigned* flags, int dmask)
{
  const int bid = blockIdx.x;
  const bool isL0 = bid < L0_NBLK;
  const int tid = threadIdx.x;
  const int w = tid >> 6;         // K-slice 0..3 (256 elems each)
  const int lane = tid & 63;
  const int l15 = lane & 15;
  const int lq = lane >> 4;
  const int swz = l15 & 7;
  const int dlag = dmask;         // D-1 run-ahead slack

  int b0, n0, bs, cs;
  if (isL0) { bs = bid >> 4; cs = bid & 15; b0 = bs * 16; n0 = cs * 64; }
  else { const int b2 = bid - L0_NBLK; bs = b2 >> 5; cs = b2 & 31; b0 = bs * 16; n0 = cs * 32; }

  unsigned* fbase = flags + bs * 48 * FLAG_STRIDE;
  unsigned* myflag = fbase + (isL0 ? cs : 16 + cs) * FLAG_STRIDE;

  const unsigned HBYT = (unsigned)(dmask + 1) * BH * 2u;
  const i32x4 srd_h0 = make_srd(h0buf, HBYT);
  const i32x4 srd_h1 = make_srd(h1buf, HBYT);

  __shared__ __align__(16) f16 Ws[2 * 32 * RNN_H];   // 128 KiB weights (fp16, swizzled)
  __shared__ float red[4][16][64];                    // 16 KiB K-split reduction

  // ---- stage weights fp32 -> fp16 into LDS, 16B-chunk swizzle: chunk c of row n -> c^(n&7)
  if (isL0) {
    const int n = tid >> 2;             // 0..63
    const int kb = (tid & 3) * 256;
    const float* src = Whh0 + (size_t)(n0 + n) * RNN_H + kb;
    f16* dst = Ws + n * RNN_H;
    #pragma unroll 4
    for (int j = 0; j < 32; ++j) {
      float tmp[8];
      *(float4*)&tmp[0] = *(const float4*)(src + j * 8);
      *(float4*)&tmp[4] = *(const float4*)(src + j * 8 + 4);
      const int c = (kb >> 3) + j;
      *(f16x8*)&dst[((c ^ (n & 7)) << 3)] = cvt8f(tmp);
    }
  } else {
    const int n = tid >> 3;             // 0..31
    const int kb = (tid & 7) * 128;
    #pragma unroll
    for (int m = 0; m < 2; ++m) {
      const float* src = (m ? Whh1 : Wih1) + (size_t)(n0 + n) * RNN_H + kb;
      f16* dst = Ws + m * 32 * RNN_H + n * RNN_H;
      #pragma unroll 4
      for (int j = 0; j < 16; ++j) {
        float tmp[8];
        *(float4*)&tmp[0] = *(const float4*)(src + j * 8);
        *(float4*)&tmp[4] = *(const float4*)(src + j * 8 + 4);
        const int c = (kb >> 3) + j;
        *(f16x8*)&dst[((c ^ (n & 7)) << 3)] = cvt8f(tmp);
      }
    }
  }

  float* hT = outs + OUTS_ELEMS;

  // combine-phase role
  int ccol, crg;
  float bias1s = 0.f;
  if (isL0) { ccol = tid & 63; crg = tid >> 6; }        // rows crg*4 + r
  else      { ccol = tid & 31; crg = tid >> 5;          // rows crg*2 + r
              bias1s = bih1[n0 + ccol] + bhh1[n0 + ccol]; }
  __syncthreads();

  if (isL0) {
    float a0v[4];
    #pragma unroll
    for (int r = 0; r < 4; ++r)
      a0v[r] = outs[((size_t)(b0 + crg * 4 + r) * RNN_S + 0) * RNN_H + n0 + ccol];

    for (int p = 0; p < RNN_S; ++p) {
      // need: L0grp finished step p-1 (flags >= p); WAR vs L1 readers of h0(p-D)
      waitflags(fbase, p, p - dlag);
      if (p > 0) {
        const int hb = (((p - 1) & dmask) * BH + (b0 + l15) * RNN_H + w * 256 + lq * 8) * 2;
        f32x4 acc[4] = {};
        #pragma unroll
        for (int ks = 0; ks < 8; ++ks) {
          f16x8 hx = ld_h(srd_h0, hb + ks * 64);
          const int c = ((w * 32 + ks * 4 + lq) ^ swz) << 3;
          #pragma unroll
          for (int ct = 0; ct < 4; ++ct)
            acc[ct] = mfma16f(hx, *(const f16x8*)&Ws[(ct * 16 + l15) * RNN_H + c], acc[ct]);
        }
        #pragma unroll
        for (int ct = 0; ct < 4; ++ct)
          #pragma unroll
          for (int r = 0; r < 4; ++r)
            red[w][lq * 4 + r][ct * 16 + l15] = acc[ct][r];
      }
      __syncthreads();
      float vals[4];
      #pragma unroll
      for (int r = 0; r < 4; ++r) {
        const int row = crg * 4 + r;
        float s = a0v[r];
        if (p > 0)
          s += red[0][row][ccol] + red[1][row][ccol] + red[2][row][ccol] + red[3][row][ccol];
        vals[r] = tanhf(s);
        st_sys_u16(&h0buf[(size_t)(p & dmask) * BH + (size_t)(b0 + row) * RNN_H + n0 + ccol],
                   f16bits(vals[r]));
      }
      if (p == RNN_S - 1) {
        #pragma unroll
        for (int r = 0; r < 4; ++r)
          hT[(size_t)(b0 + crg * 4 + r) * RNN_H + n0 + ccol] = vals[r];
      }
      if (p + 1 < RNN_S) {
        #pragma unroll
        for (int r = 0; r < 4; ++r)
          a0v[r] = outs[((size_t)(b0 + crg * 4 + r) * RNN_S + (p + 1)) * RNN_H + n0 + ccol];
      }
      publish(myflag, (unsigned)(p + 1));
    }
  } else {
    for (int t = 0; t < RNN_S; ++t) {
      // need: h0(t) written (L0grp >= t+1); h1(t-1) written (L1grp >= t)
      waitflags(fbase, t + 1, t);
      const int hb0 = ((t & dmask) * BH + (b0 + l15) * RNN_H + w * 256 + lq * 8) * 2;
      f32x4 acc[2] = {};
      if (t > 0) {
        const int hb1 = (((t - 1) & dmask) * BH + (b0 + l15) * RNN_H + w * 256 + lq * 8) * 2;
        #pragma unroll
        for (int ks = 0; ks < 8; ++ks) {
          f16x8 hx = ld_h(srd_h0, hb0 + ks * 64);
          f16x8 gx = ld_h(srd_h1, hb1 + ks * 64);
          const int c = ((w * 32 + ks * 4 + lq) ^ swz) << 3;
          #pragma unroll
          for (int ct = 0; ct < 2; ++ct) {
            acc[ct] = mfma16f(hx, *(const f16x8*)&Ws[(ct * 16 + l15) * RNN_H + c], acc[ct]);
            acc[ct] = mfma16f(gx, *(const f16x8*)&Ws[32 * RNN_H + (ct * 16 + l15) * RNN_H + c], acc[ct]);
          }
        }
      } else {
        #pragma unroll
        for (int ks = 0; ks < 8; ++ks) {
          f16x8 hx = ld_h(srd_h0, hb0 + ks * 64);
          const int c = ((w * 32 + ks * 4 + lq) ^ swz) << 3;
          #pragma unroll
          for (int ct = 0; ct < 2; ++ct)
            acc[ct] = mfma16f(hx, *(const f16x8*)&Ws[(ct * 16 + l15) * RNN_H + c], acc[ct]);
        }
      }
      #pragma unroll
      for (int ct = 0; ct < 2; ++ct)
        #pragma unroll
        for (int r = 0; r < 4; ++r)
          red[w][lq * 4 + r][ct * 16 + l15] = acc[ct][r];
      __syncthreads();
      #pragma unroll
      for (int r = 0; r < 2; ++r) {
        const int row = crg * 2 + r;
        float s = bias1s + red[0][row][ccol] + red[1][row][ccol]
                         + red[2][row][ccol] + red[3][row][ccol];
        const float v = tanhf(s);
        st_sys_u16(&h1buf[(size_t)(t & dmask) * BH + (size_t)(b0 + row) * RNN_H + n0 + ccol],
                   f16bits(v));
        outs[((size_t)(b0 + row) * RNN_S + t) * RNN_H + n0 + ccol] = v;
        if (t == RNN_S - 1)
          hT[(size_t)BH + (size_t)(b0 + row) * RNN_H + n0 + ccol] = v;
      }
      publish(myflag, (unsigned)(t + 1));
    }
  }
}

extern "C" void kernel_launch(void* const* d_in, const int* in_sizes, int n_in,
                              void* d_out, int out_size, void* d_ws, size_t ws_size,
                              hipStream_t stream) {
  const float* x    = (const float*)d_in[0];
  const float* Wih0 = (const float*)d_in[1];
  const float* bih0 = (const float*)d_in[2];
  const float* Whh0 = (const float*)d_in[3];
  const float* bhh0 = (const float*)d_in[4];
  const float* Wih1 = (const float*)d_in[5];
  const float* bih1 = (const float*)d_in[6];
  const float* Whh1 = (const float*)d_in[7];
  const float* bhh1 = (const float*)d_in[8];
  float* outs = (float*)d_out;

  // ws layout: [flags 32KiB][h0buf D*128KiB][h1buf D*128KiB]
  const size_t flagBytes = 32768;
  const size_t need4 = flagBytes + 2 * (size_t)4 * BH * sizeof(f16);   // ~1.03 MiB
  const int D = (ws_size >= need4) ? 4 : 2;
  unsigned* flags = (unsigned*)d_ws;
  f16* h0buf = (f16*)((char*)d_ws + flagBytes);
  f16* h1buf = h0buf + (size_t)D * BH;

  a0_gemm<<<2048, 256, 0, stream>>>(x, Wih0, bih0, bhh0, outs, flags);
  rnn_rec<<<NBLK, 256, 0, stream>>>(Whh0, Wih1, bih1, Whh1, bhh1, outs,
                                    h0buf, h1buf, flags, D - 1);
}